// Round 11
// baseline (235.884 us; speedup 1.0000x reference)
//
#include <hip/hip_runtime.h>

#define N_NODES 100000
#define N_EDGES 1600000
#define DIM 128

#define BSHIFT 8
#define BNODES 256
#define NBUCK 391     // ceil(100000/256)
#define BCAP  4608    // padded bucket capacity
#define PCHUNK 4096
#define NB_PART ((N_EDGES + PCHUNK - 1) / PCHUNK)  // 391

#define NSLICE 8      // 16-col slices; slice s = blockIdx%8 -> XCD s (heuristic)
#define SLICE_ELEMS ((size_t)N_NODES * 16)
#define NTILE ((N_NODES + 127) / 128)   // 782 node-tiles of 128

#define GTILES 1563
#define GGRID  782

typedef short s16x8 __attribute__((ext_vector_type(8)));
typedef float f32x4 __attribute__((ext_vector_type(4)));

__device__ __forceinline__ unsigned short f2bf(float f) {
    unsigned u = __float_as_uint(f);
    u += 0x7fffu + ((u >> 16) & 1u);   // RNE
    return (unsigned short)(u >> 16);
}
__device__ __forceinline__ float bflo(unsigned u) { return __uint_as_float(u << 16); }
__device__ __forceinline__ float bfhi(unsigned u) { return __uint_as_float(u & 0xffff0000u); }

__device__ __forceinline__ void acc8(float (&a)[8], uint4 v, float w) {
    a[0] = fmaf(bflo(v.x), w, a[0]); a[1] = fmaf(bfhi(v.x), w, a[1]);
    a[2] = fmaf(bflo(v.y), w, a[2]); a[3] = fmaf(bfhi(v.y), w, a[3]);
    a[4] = fmaf(bflo(v.z), w, a[4]); a[5] = fmaf(bfhi(v.z), w, a[5]);
    a[6] = fmaf(bflo(v.w), w, a[6]); a[7] = fmaf(bfhi(v.w), w, a[7]);
}

// ---------------- CSR build (padded buckets) ----------------

__global__ void k_zero(int* __restrict__ gcur) {
    int t = blockIdx.x * blockDim.x + threadIdx.x;
    if (t < NBUCK) gcur[t] = t * BCAP;
}

__device__ __forceinline__ void part_body(char* smem, int bid,
                                          const int* __restrict__ src,
                                          const int* __restrict__ dst,
                                          int* __restrict__ gcur,
                                          int2* __restrict__ ebuf) {
    int* hist = (int*)smem;
    int* gbase = hist + NBUCK;
    int tid = threadIdx.x;
    long e0 = (long)bid * PCHUNK;
    int n = min(PCHUNK, (int)(N_EDGES - e0));
    for (int b = tid; b < NBUCK; b += 256) hist[b] = 0;
    __syncthreads();

    int mys[16], myd[16];
#pragma unroll
    for (int k = 0; k < 16; ++k) {
        int idx = k * 256 + tid;
        if (idx < n) {
            mys[k] = src[e0 + idx];
            myd[k] = dst[e0 + idx];
            atomicAdd(&hist[myd[k] >> BSHIFT], 1);
        } else {
            myd[k] = -1;
        }
    }
    __syncthreads();
    for (int b = tid; b < NBUCK; b += 256) {
        gbase[b] = hist[b] ? atomicAdd(&gcur[b], hist[b]) : 0;
        hist[b] = 0;
    }
    __syncthreads();
#pragma unroll
    for (int k = 0; k < 16; ++k) {
        if (myd[k] >= 0) {
            int b = myd[k] >> BSHIFT;
            int slot = gbase[b] + atomicAdd(&hist[b], 1);
            ebuf[slot] = make_int2(mys[k], myd[k]);
        }
    }
}

// ---- GEMM body: h1s(bf16, slice-major [8][N][16]) = x @ W1 ----
__device__ __forceinline__ void gemm_body(char* smem, int bid,
                                          const float* __restrict__ x,
                                          const float* __restrict__ W1,
                                          unsigned short* __restrict__ h1s) {
    unsigned short* Wt = (unsigned short*)smem;           // 32 KB
    int tid = threadIdx.x;
    for (int idx = tid; idx < DIM * DIM; idx += 256) {
        int k = idx >> 7, c = idx & 127;
        Wt[c * 128 + (k ^ ((c & 7) << 3))] = f2bf(W1[idx]);
    }
    __syncthreads();

    int wv = tid >> 6, lane = tid & 63;
    int g = lane >> 4, tl = lane & 15;
    unsigned short* cst = (unsigned short*)(smem + 32768 + wv * 4096);

    int s2 = tl >> 1, hh = tl & 1;   // slice / col-half owned by this lane at store

    for (int tile = bid; tile < GTILES; tile += GGRID) {
        int rb = tile * 64 + wv * 16;
        if (rb >= N_NODES) continue;

        s16x8 afrag[4];
        const float* xrow = x + (size_t)(rb + tl) * DIM + g * 8;
#pragma unroll
        for (int kc = 0; kc < 4; ++kc) {
            float4 p0 = *(const float4*)(xrow + kc * 32);
            float4 p1 = *(const float4*)(xrow + kc * 32 + 4);
            s16x8 a;
            a[0] = (short)f2bf(p0.x); a[1] = (short)f2bf(p0.y);
            a[2] = (short)f2bf(p0.z); a[3] = (short)f2bf(p0.w);
            a[4] = (short)f2bf(p1.x); a[5] = (short)f2bf(p1.y);
            a[6] = (short)f2bf(p1.z); a[7] = (short)f2bf(p1.w);
            afrag[kc] = a;
        }

        f32x4 acc[8];
#pragma unroll
        for (int ct = 0; ct < 8; ++ct) acc[ct] = (f32x4)0.0f;
#pragma unroll
        for (int kc = 0; kc < 4; ++kc) {
#pragma unroll
            for (int ct = 0; ct < 8; ++ct) {
                int crow = ct * 16 + tl;
                int boff = crow * 256 + ((kc * 64 + g * 16) ^ ((crow & 7) << 4));
                s16x8 b = *(const s16x8*)((const char*)Wt + boff);
                acc[ct] = __builtin_amdgcn_mfma_f32_16x16x32_bf16(afrag[kc], b, acc[ct], 0, 0, 0);
            }
        }

#pragma unroll
        for (int ct = 0; ct < 8; ++ct) {
#pragma unroll
            for (int r = 0; r < 4; ++r) {
                float own = acc[ct][r];
                float oth = __shfl_xor(own, 1, 64);
                if ((lane & 1) == 0) {
                    unsigned pk = (unsigned)f2bf(own) | ((unsigned)f2bf(oth) << 16);
                    int row = g * 4 + r;
                    int col = ct * 16 + tl;
                    *(unsigned*)&cst[row * 128 + (col ^ (row << 3))] = pk;
                }
            }
        }
        asm volatile("s_waitcnt lgkmcnt(0)" ::: "memory");

#pragma unroll
        for (int c = 0; c < 4; ++c) {
            int row = c * 4 + g;
            uint4 v = *(const uint4*)&cst[row * 128 + ((tl ^ row) * 8)];
            size_t n = (size_t)(rb + row);
            *(uint4*)(h1s + (size_t)s2 * SLICE_ELEMS + n * 16 + hh * 8) = v;
        }
    }
}

__global__ __launch_bounds__(256) void k_part(const int* __restrict__ src,
                                              const int* __restrict__ dst,
                                              int* __restrict__ gcur,
                                              int2* __restrict__ ebuf) {
    __shared__ __align__(16) char smem[2 * NBUCK * 4 + 16];
    part_body(smem, blockIdx.x, src, dst, gcur, ebuf);
}

__global__ __launch_bounds__(256) void k_gemm(const float* __restrict__ x,
                                              const float* __restrict__ W1,
                                              unsigned short* __restrict__ h1s) {
    __shared__ __align__(16) char smem[49152];
    gemm_body(smem, blockIdx.x, x, W1, h1s);
}

__global__ __launch_bounds__(256) void k_pg(const int* __restrict__ src,
                                            const int* __restrict__ dst,
                                            int* __restrict__ gcur,
                                            int2* __restrict__ ebuf,
                                            const float* __restrict__ x,
                                            const float* __restrict__ W1,
                                            unsigned short* __restrict__ h1s) {
    __shared__ __align__(16) char smem[49152];
    if (blockIdx.x < NB_PART) part_body(smem, blockIdx.x, src, dst, gcur, ebuf);
    else                      gemm_body(smem, blockIdx.x - NB_PART, x, W1, h1s);
}

__global__ __launch_bounds__(256) void k_csrA(const int2* __restrict__ ebuf,
                                              const int* __restrict__ gcur,
                                              int* __restrict__ rp,
                                              int* __restrict__ cnt,
                                              float* __restrict__ dinv) {
    __shared__ int lcnt[BNODES];
    __shared__ int psum[BNODES];
    int b = blockIdx.x, t = threadIdx.x;
    int node0 = b << BSHIFT;
    lcnt[t] = 0;
    __syncthreads();
    int base = b * BCAP, end = gcur[b];
    for (int e = base + t; e < end; e += 256)
        atomicAdd(&lcnt[ebuf[e].y - node0], 1);
    __syncthreads();
    int c = lcnt[t];
    psum[t] = c;
    __syncthreads();
    for (int s = 1; s < 256; s <<= 1) {
        int u = (t >= s) ? psum[t - s] : 0;
        __syncthreads();
        psum[t] += u;
        __syncthreads();
    }
    int node = node0 + t;
    if (node < N_NODES) {
        rp[node] = base + psum[t] - c;
        cnt[node] = c;
        dinv[node] = rsqrtf((float)(c + 1));
    }
}

// per-bucket CSR emit; writes int2 csrw (for agg2) + compact int csrs (for agg1s)
__global__ __launch_bounds__(256) void k_csrB(const int2* __restrict__ ebuf,
                                              const int* __restrict__ gcur,
                                              const int* __restrict__ rp,
                                              const float* __restrict__ dinv,
                                              int2* __restrict__ csrw,
                                              int* __restrict__ csrs) {
    __shared__ int lcur[BNODES];
    __shared__ float ldv[BNODES];
    int b = blockIdx.x, t = threadIdx.x;
    int node0 = b << BSHIFT;
    int base = b * BCAP, end = gcur[b];
    int node = node0 + t;
    if (node < N_NODES) { lcur[t] = rp[node] - base; ldv[t] = dinv[node]; }
    __syncthreads();
    for (int e = base + t; e < end; e += 256) {
        int2 d = ebuf[e];
        int l = d.y - node0;
        float w = dinv[d.x] * ldv[l];
        int p = atomicAdd(&lcur[l], 1);
        csrw[base + p] = make_int2(d.x, __float_as_int(w));
        csrs[base + p] = d.x;
    }
}

// ---------------- agg1 sliced v2: 2 lanes/node, serial edges, no ballots ----------------
// slice s = blockIdx%8 (XCD-pinned by round-robin dispatch); lane h owns 8 cols.
// w recomputed from dinv (L2-resident 400KB) -> meta stream is 4B/edge.

__global__ __launch_bounds__(256) void k_agg1s(const unsigned short* __restrict__ h1s,
                                               const float* __restrict__ dinv,
                                               const int* __restrict__ rp,
                                               const int* __restrict__ cnt,
                                               const int* __restrict__ csrs,
                                               const float* __restrict__ b1,
                                               const float* __restrict__ W2,
                                               float* __restrict__ zpart) {
    int s = blockIdx.x & 7;
    int tile0 = blockIdx.x >> 3;          // 0..255
    int lane = threadIdx.x & 63;
    int wv = threadIdx.x >> 6;
    int h = lane & 1;
    int nloc = wv * 32 + (lane >> 1);     // node within 128-node tile
    const unsigned short* hs = h1s + (size_t)s * SLICE_ELEMS + h * 8;
    int cb = s * 16 + h * 8;

    for (int tile = tile0; tile < NTILE; tile += 256) {
        int i = tile * 128 + nloc;
        if (i >= N_NODES) continue;
        float di = dinv[i];
        int beg = rp[i], end = beg + cnt[i];
        float a[8];
#pragma unroll
        for (int q = 0; q < 8; ++q) a[q] = 0.f;

        int j = beg;
        for (; j + 4 <= end; j += 4) {
            int s0 = csrs[j], s1 = csrs[j + 1], s2 = csrs[j + 2], s3 = csrs[j + 3];
            uint4 v0 = *(const uint4*)(hs + (size_t)s0 * 16);
            uint4 v1 = *(const uint4*)(hs + (size_t)s1 * 16);
            uint4 v2 = *(const uint4*)(hs + (size_t)s2 * 16);
            uint4 v3 = *(const uint4*)(hs + (size_t)s3 * 16);
            float w0 = dinv[s0] * di, w1 = dinv[s1] * di;
            float w2 = dinv[s2] * di, w3 = dinv[s3] * di;
            acc8(a, v0, w0);
            acc8(a, v1, w1);
            acc8(a, v2, w2);
            acc8(a, v3, w3);
        }
        for (; j < end; ++j) {
            int s0 = csrs[j];
            uint4 v0 = *(const uint4*)(hs + (size_t)s0 * 16);
            acc8(a, v0, dinv[s0] * di);
        }

        uint4 vs = *(const uint4*)(hs + (size_t)i * 16);
        float sii = di * di;
        float4 bA = *(const float4*)(b1 + cb);
        float4 bB = *(const float4*)(b1 + cb + 4);
        float4 wA = *(const float4*)(W2 + cb);
        float4 wB = *(const float4*)(W2 + cb + 4);
        float part = 0.f;
        part += fmaxf(fmaf(bflo(vs.x), sii, a[0]) + bA.x, 0.f) * wA.x;
        part += fmaxf(fmaf(bfhi(vs.x), sii, a[1]) + bA.y, 0.f) * wA.y;
        part += fmaxf(fmaf(bflo(vs.y), sii, a[2]) + bA.z, 0.f) * wA.z;
        part += fmaxf(fmaf(bfhi(vs.y), sii, a[3]) + bA.w, 0.f) * wA.w;
        part += fmaxf(fmaf(bflo(vs.z), sii, a[4]) + bB.x, 0.f) * wB.x;
        part += fmaxf(fmaf(bfhi(vs.z), sii, a[5]) + bB.y, 0.f) * wB.y;
        part += fmaxf(fmaf(bflo(vs.w), sii, a[6]) + bB.z, 0.f) * wB.z;
        part += fmaxf(fmaf(bfhi(vs.w), sii, a[7]) + bB.w, 0.f) * wB.w;
        part += __shfl_xor(part, 1, 64);   // combine the two col-halves
        if (h == 0) zpart[(size_t)s * N_NODES + i] = part;
    }
}

// z[i] = sum_s zpart[s][i]
__global__ void k_zred(const float* __restrict__ zpart, float* __restrict__ z) {
    int i = blockIdx.x * blockDim.x + threadIdx.x;
    if (i < N_NODES) {
        float t = 0.f;
#pragma unroll
        for (int s = 0; s < NSLICE; ++s) t += zpart[(size_t)s * N_NODES + i];
        z[i] = t;
    }
}

// ---------------- agg2 (unchanged) ----------------

__global__ __launch_bounds__(256) void k_agg2(const float* __restrict__ zin,
                                              const float* __restrict__ dinv,
                                              const int* __restrict__ rp,
                                              const int* __restrict__ cnt,
                                              const int2* __restrict__ csrw,
                                              const float* __restrict__ b2,
                                              float* __restrict__ out) {
    int i = blockIdx.x * blockDim.x + threadIdx.x;
    if (i >= N_NODES) return;
    float di = dinv[i];
    int beg = rp[i], end = beg + cnt[i];
    float acc = 0.f;
    int j = beg;
    for (; j + 4 <= end; j += 4) {
        int2 e0 = csrw[j], e1 = csrw[j + 1], e2 = csrw[j + 2], e3 = csrw[j + 3];
        float z0 = zin[e0.x], z1 = zin[e1.x], z2 = zin[e2.x], z3 = zin[e3.x];
        acc = fmaf(z0, __int_as_float(e0.y), acc);
        acc = fmaf(z1, __int_as_float(e1.y), acc);
        acc = fmaf(z2, __int_as_float(e2.y), acc);
        acc = fmaf(z3, __int_as_float(e3.y), acc);
    }
    for (; j < end; ++j) {
        int2 e = csrw[j];
        acc = fmaf(zin[e.x], __int_as_float(e.y), acc);
    }
    out[i] = acc + zin[i] * di * di + b2[0];
}

// ---------------- launch ----------------

extern "C" void kernel_launch(void* const* d_in, const int* in_sizes, int n_in,
                              void* d_out, int out_size, void* d_ws, size_t ws_size,
                              hipStream_t stream) {
    const float* x  = (const float*)d_in[0];
    const int*   ei = (const int*)d_in[1];
    const float* W1 = (const float*)d_in[2];
    const float* b1 = (const float*)d_in[3];
    const float* W2 = (const float*)d_in[4];
    const float* b2 = (const float*)d_in[5];
    float* out = (float*)d_out;

    const int* src = ei;
    const int* dst = ei + N_EDGES;

    char* ws = (char*)d_ws;
    size_t o = 0;
    auto take = [&](size_t bytes) { char* p = ws + o; o += (bytes + 255) & ~(size_t)255; return p; };
    int*   cnt   = (int*)take(sizeof(int) * N_NODES);
    int*   rp    = (int*)take(sizeof(int) * N_NODES);
    int*   gcur  = (int*)take(sizeof(int) * (NBUCK + 1));
    float* dinv  = (float*)take(sizeof(float) * N_NODES);
    float* z     = (float*)take(sizeof(float) * N_NODES);
    float* zpart = (float*)take(sizeof(float) * (size_t)NSLICE * N_NODES);
    int2*  csrw  = (int2*)take(sizeof(int2) * (size_t)NBUCK * BCAP);
    int*   csrs  = (int*)take(sizeof(int) * (size_t)NBUCK * BCAP);
    unsigned short* h1s = (unsigned short*)take(sizeof(unsigned short) * (size_t)NSLICE * SLICE_ELEMS);
    int2* ebuf_sep = (int2*)take(sizeof(int2) * (size_t)NBUCK * BCAP);
    bool fused = (o <= ws_size);
    int2* ebuf = fused ? ebuf_sep : (int2*)h1s;  // fallback: alias h1s (lifetimes disjoint)

    const int NB_N = (N_NODES + 255) / 256;

    k_zero<<<2, 256, 0, stream>>>(gcur);
    if (fused) {
        k_pg<<<NB_PART + GGRID, 256, 0, stream>>>(src, dst, gcur, ebuf, x, W1, h1s);
        k_csrA<<<NBUCK, 256, 0, stream>>>(ebuf, gcur, rp, cnt, dinv);
        k_csrB<<<NBUCK, 256, 0, stream>>>(ebuf, gcur, rp, dinv, csrw, csrs);
    } else {
        k_part<<<NB_PART, 256, 0, stream>>>(src, dst, gcur, ebuf);
        k_csrA<<<NBUCK, 256, 0, stream>>>(ebuf, gcur, rp, cnt, dinv);
        k_csrB<<<NBUCK, 256, 0, stream>>>(ebuf, gcur, rp, dinv, csrw, csrs);
        k_gemm<<<GGRID, 256, 0, stream>>>(x, W1, h1s);  // after last ebuf read
    }
    k_agg1s<<<2048, 256, 0, stream>>>(h1s, dinv, rp, cnt, csrs, b1, W2, zpart);
    k_zred<<<NB_N, 256, 0, stream>>>(zpart, z);
    k_agg2<<<NB_N, 256, 0, stream>>>(z, dinv, rp, cnt, csrw, b2, out);
}

// Round 12
// 142.058 us; speedup vs baseline: 1.6605x; 1.6605x over previous
//
#include <hip/hip_runtime.h>

#define N_NODES 100000
#define N_EDGES 1600000
#define DIM 128

#define BSHIFT 8
#define BNODES 256
#define NBUCK 391     // ceil(100000/256)
#define BCAP  4608    // padded bucket capacity
#define PCHUNK 4096
#define NB_PART ((N_EDGES + PCHUNK - 1) / PCHUNK)  // 391

#define GTILES 1563   // ceil(100000/64)
#define GGRID  1563   // one tile per block

typedef short s16x8 __attribute__((ext_vector_type(8)));
typedef float f32x4 __attribute__((ext_vector_type(4)));

__device__ __forceinline__ unsigned short f2bf(float f) {
    unsigned u = __float_as_uint(f);
    u += 0x7fffu + ((u >> 16) & 1u);   // RNE
    return (unsigned short)(u >> 16);
}
__device__ __forceinline__ float bflo(unsigned u) { return __uint_as_float(u << 16); }
__device__ __forceinline__ float bfhi(unsigned u) { return __uint_as_float(u & 0xffff0000u); }

__device__ __forceinline__ void acc8(float (&a)[8], uint4 v, float w) {
    a[0] = fmaf(bflo(v.x), w, a[0]); a[1] = fmaf(bfhi(v.x), w, a[1]);
    a[2] = fmaf(bflo(v.y), w, a[2]); a[3] = fmaf(bfhi(v.y), w, a[3]);
    a[4] = fmaf(bflo(v.z), w, a[4]); a[5] = fmaf(bfhi(v.z), w, a[5]);
    a[6] = fmaf(bflo(v.w), w, a[6]); a[7] = fmaf(bfhi(v.w), w, a[7]);
}

// ---------------- CSR build (padded buckets) ----------------

__global__ void k_zero(int* __restrict__ gcur) {
    int t = blockIdx.x * blockDim.x + threadIdx.x;
    if (t < NBUCK) gcur[t] = t * BCAP;
}

__device__ __forceinline__ void part_body(char* smem, int bid,
                                          const int* __restrict__ src,
                                          const int* __restrict__ dst,
                                          int* __restrict__ gcur,
                                          int2* __restrict__ ebuf) {
    int* hist = (int*)smem;
    int* gbase = hist + NBUCK;
    int tid = threadIdx.x;
    long e0 = (long)bid * PCHUNK;
    int n = min(PCHUNK, (int)(N_EDGES - e0));
    for (int b = tid; b < NBUCK; b += 256) hist[b] = 0;
    __syncthreads();

    int mys[16], myd[16];
#pragma unroll
    for (int k = 0; k < 16; ++k) {
        int idx = k * 256 + tid;
        if (idx < n) {
            mys[k] = src[e0 + idx];
            myd[k] = dst[e0 + idx];
            atomicAdd(&hist[myd[k] >> BSHIFT], 1);
        } else {
            myd[k] = -1;
        }
    }
    __syncthreads();
    for (int b = tid; b < NBUCK; b += 256) {
        gbase[b] = hist[b] ? atomicAdd(&gcur[b], hist[b]) : 0;
        hist[b] = 0;
    }
    __syncthreads();
#pragma unroll
    for (int k = 0; k < 16; ++k) {
        if (myd[k] >= 0) {
            int b = myd[k] >> BSHIFT;
            int slot = gbase[b] + atomicAdd(&hist[b], 1);
            ebuf[slot] = make_int2(mys[k], myd[k]);
        }
    }
}

// ---- GEMM body: h1(bf16, row-major [N][128]) = x @ W1 via bf16 MFMA ----
__device__ __forceinline__ void gemm_body(char* smem, int bid,
                                          const float* __restrict__ x,
                                          const float* __restrict__ W1,
                                          unsigned short* __restrict__ h1) {
    unsigned short* Wt = (unsigned short*)smem;           // 32 KB
    int tid = threadIdx.x;
    for (int idx = tid; idx < DIM * DIM; idx += 256) {
        int k = idx >> 7, c = idx & 127;
        Wt[c * 128 + (k ^ ((c & 7) << 3))] = f2bf(W1[idx]);
    }
    __syncthreads();

    int wv = tid >> 6, lane = tid & 63;
    int g = lane >> 4, tl = lane & 15;
    unsigned short* cst = (unsigned short*)(smem + 32768 + wv * 4096);

    for (int tile = bid; tile < GTILES; tile += GGRID) {
        int rb = tile * 64 + wv * 16;
        if (rb >= N_NODES) continue;

        s16x8 afrag[4];
        const float* xrow = x + (size_t)(rb + tl) * DIM + g * 8;
#pragma unroll
        for (int kc = 0; kc < 4; ++kc) {
            float4 p0 = *(const float4*)(xrow + kc * 32);
            float4 p1 = *(const float4*)(xrow + kc * 32 + 4);
            s16x8 a;
            a[0] = (short)f2bf(p0.x); a[1] = (short)f2bf(p0.y);
            a[2] = (short)f2bf(p0.z); a[3] = (short)f2bf(p0.w);
            a[4] = (short)f2bf(p1.x); a[5] = (short)f2bf(p1.y);
            a[6] = (short)f2bf(p1.z); a[7] = (short)f2bf(p1.w);
            afrag[kc] = a;
        }

        f32x4 acc[8];
#pragma unroll
        for (int ct = 0; ct < 8; ++ct) acc[ct] = (f32x4)0.0f;
#pragma unroll
        for (int kc = 0; kc < 4; ++kc) {
#pragma unroll
            for (int ct = 0; ct < 8; ++ct) {
                int crow = ct * 16 + tl;
                int boff = crow * 256 + ((kc * 64 + g * 16) ^ ((crow & 7) << 4));
                s16x8 b = *(const s16x8*)((const char*)Wt + boff);
                acc[ct] = __builtin_amdgcn_mfma_f32_16x16x32_bf16(afrag[kc], b, acc[ct], 0, 0, 0);
            }
        }

#pragma unroll
        for (int ct = 0; ct < 8; ++ct) {
#pragma unroll
            for (int r = 0; r < 4; ++r) {
                float own = acc[ct][r];
                float oth = __shfl_xor(own, 1, 64);
                if ((lane & 1) == 0) {
                    unsigned pk = (unsigned)f2bf(own) | ((unsigned)f2bf(oth) << 16);
                    int row = g * 4 + r;
                    int col = ct * 16 + tl;
                    *(unsigned*)&cst[row * 128 + (col ^ (row << 3))] = pk;
                }
            }
        }
        asm volatile("s_waitcnt lgkmcnt(0)" ::: "memory");

        unsigned short* dstp = h1 + (size_t)rb * DIM;
#pragma unroll
        for (int c = 0; c < 4; ++c) {
            int row = c * 4 + g;
            uint4 v = *(const uint4*)&cst[row * 128 + ((tl ^ row) * 8)];
            *(uint4*)(dstp + c * 512 + lane * 8) = v;
        }
    }
}

__global__ __launch_bounds__(256) void k_part(const int* __restrict__ src,
                                              const int* __restrict__ dst,
                                              int* __restrict__ gcur,
                                              int2* __restrict__ ebuf) {
    __shared__ __align__(16) char smem[2 * NBUCK * 4 + 16];
    part_body(smem, blockIdx.x, src, dst, gcur, ebuf);
}

__global__ __launch_bounds__(256) void k_gemm(const float* __restrict__ x,
                                              const float* __restrict__ W1,
                                              unsigned short* __restrict__ h1) {
    __shared__ __align__(16) char smem[49152];
    gemm_body(smem, blockIdx.x, x, W1, h1);
}

// fused: blocks [0,NB_PART) partition edges, rest do the GEMM
__global__ __launch_bounds__(256) void k_pg(const int* __restrict__ src,
                                            const int* __restrict__ dst,
                                            int* __restrict__ gcur,
                                            int2* __restrict__ ebuf,
                                            const float* __restrict__ x,
                                            const float* __restrict__ W1,
                                            unsigned short* __restrict__ h1) {
    __shared__ __align__(16) char smem[49152];
    if (blockIdx.x < NB_PART) part_body(smem, blockIdx.x, src, dst, gcur, ebuf);
    else                      gemm_body(smem, blockIdx.x - NB_PART, x, W1, h1);
}

// merged CSR: one block per bucket — count, scan, emit src-only lists.
// (weights recomputed downstream from dinv; whole bucket is self-contained)
__global__ __launch_bounds__(256) void k_csr(const int2* __restrict__ ebuf,
                                             const int* __restrict__ gcur,
                                             int* __restrict__ rp,
                                             int* __restrict__ cnt,
                                             float* __restrict__ dinv,
                                             int* __restrict__ csrs) {
    __shared__ int lcnt[BNODES];
    __shared__ int lcur[BNODES];
    int b = blockIdx.x, t = threadIdx.x;
    int node0 = b << BSHIFT;
    lcnt[t] = 0;
    __syncthreads();
    int base = b * BCAP, end = gcur[b];
    for (int e = base + t; e < end; e += 256)
        atomicAdd(&lcnt[ebuf[e].y - node0], 1);
    __syncthreads();
    int c = lcnt[t];
    lcur[t] = c;
    __syncthreads();
    for (int s = 1; s < 256; s <<= 1) {
        int u = (t >= s) ? lcur[t - s] : 0;
        __syncthreads();
        lcur[t] += u;
        __syncthreads();
    }
    int excl = lcur[t] - c;   // own slot only; safe to overwrite below
    lcur[t] = excl;           // becomes emit cursor
    int node = node0 + t;
    if (node < N_NODES) {
        rp[node] = base + excl;
        cnt[node] = c;
        dinv[node] = rsqrtf((float)(c + 1));
    }
    __syncthreads();
    for (int e = base + t; e < end; e += 256) {
        int2 d = ebuf[e];
        int p = atomicAdd(&lcur[d.y - node0], 1);
        csrs[base + p] = d.x;
    }
}

// ---------------- agg1 + b1 + ReLU + (r @ W2) -> z[N] ----------------
// R7-proven form: 16-lane group per node, full-row 256B coalesced gathers,
// unroll x4; w recomputed from dinv (L2-resident broadcast loads).

__global__ __launch_bounds__(256) void k_agg1(const unsigned short* __restrict__ h1,
                                              const float* __restrict__ dinv,
                                              const int* __restrict__ rp,
                                              const int* __restrict__ cnt,
                                              const int* __restrict__ csrs,
                                              const float* __restrict__ b1,
                                              const float* __restrict__ W2,
                                              float* __restrict__ z) {
    int lane = threadIdx.x & 63;
    int wv = threadIdx.x >> 6;
    int g = lane >> 4, tl = lane & 15;
    int i = blockIdx.x * 16 + wv * 4 + g;
    int c0 = tl * 8;
    float di = dinv[i];
    int beg = rp[i], end = beg + cnt[i];
    float a[8];
#pragma unroll
    for (int q = 0; q < 8; ++q) a[q] = 0.f;
    const unsigned short* hbase = h1 + c0;

    int j = beg;
    for (; j + 4 <= end; j += 4) {
        int s0 = csrs[j], s1 = csrs[j + 1], s2 = csrs[j + 2], s3 = csrs[j + 3];
        uint4 v0 = *(const uint4*)(hbase + (size_t)s0 * DIM);
        uint4 v1 = *(const uint4*)(hbase + (size_t)s1 * DIM);
        uint4 v2 = *(const uint4*)(hbase + (size_t)s2 * DIM);
        uint4 v3 = *(const uint4*)(hbase + (size_t)s3 * DIM);
        float w0 = dinv[s0] * di, w1 = dinv[s1] * di;
        float w2 = dinv[s2] * di, w3 = dinv[s3] * di;
        acc8(a, v0, w0);
        acc8(a, v1, w1);
        acc8(a, v2, w2);
        acc8(a, v3, w3);
    }
    for (; j < end; ++j) {
        int s0 = csrs[j];
        uint4 v0 = *(const uint4*)(hbase + (size_t)s0 * DIM);
        acc8(a, v0, dinv[s0] * di);
    }

    uint4 vs = *(const uint4*)(hbase + (size_t)i * DIM);
    float sii = di * di;
    float4 bA = *(const float4*)(b1 + c0);
    float4 bB = *(const float4*)(b1 + c0 + 4);
    float4 wA = *(const float4*)(W2 + c0);
    float4 wB = *(const float4*)(W2 + c0 + 4);
    float p = 0.f;
    p += fmaxf(fmaf(bflo(vs.x), sii, a[0]) + bA.x, 0.f) * wA.x;
    p += fmaxf(fmaf(bfhi(vs.x), sii, a[1]) + bA.y, 0.f) * wA.y;
    p += fmaxf(fmaf(bflo(vs.y), sii, a[2]) + bA.z, 0.f) * wA.z;
    p += fmaxf(fmaf(bfhi(vs.y), sii, a[3]) + bA.w, 0.f) * wA.w;
    p += fmaxf(fmaf(bflo(vs.z), sii, a[4]) + bB.x, 0.f) * wB.x;
    p += fmaxf(fmaf(bfhi(vs.z), sii, a[5]) + bB.y, 0.f) * wB.y;
    p += fmaxf(fmaf(bflo(vs.w), sii, a[6]) + bB.z, 0.f) * wB.z;
    p += fmaxf(fmaf(bfhi(vs.w), sii, a[7]) + bB.w, 0.f) * wB.w;
#pragma unroll
    for (int off = 8; off >= 1; off >>= 1) p += __shfl_xor(p, off, 64);
    if (tl == 0) z[i] = p;  // b2 added in agg2
}

// ---------------- agg2: src-only meta, w recomputed ----------------

__global__ __launch_bounds__(256) void k_agg2(const float* __restrict__ zin,
                                              const float* __restrict__ dinv,
                                              const int* __restrict__ rp,
                                              const int* __restrict__ cnt,
                                              const int* __restrict__ csrs,
                                              const float* __restrict__ b2,
                                              float* __restrict__ out) {
    int i = blockIdx.x * blockDim.x + threadIdx.x;
    if (i >= N_NODES) return;
    float di = dinv[i];
    int beg = rp[i], end = beg + cnt[i];
    float acc = 0.f;
    int j = beg;
    for (; j + 4 <= end; j += 4) {
        int s0 = csrs[j], s1 = csrs[j + 1], s2 = csrs[j + 2], s3 = csrs[j + 3];
        float z0 = zin[s0], z1 = zin[s1], z2 = zin[s2], z3 = zin[s3];
        acc = fmaf(z0, dinv[s0] * di, acc);
        acc = fmaf(z1, dinv[s1] * di, acc);
        acc = fmaf(z2, dinv[s2] * di, acc);
        acc = fmaf(z3, dinv[s3] * di, acc);
    }
    for (; j < end; ++j) {
        int s0 = csrs[j];
        acc = fmaf(zin[s0], dinv[s0] * di, acc);
    }
    out[i] = acc + zin[i] * di * di + b2[0];
}

// ---------------- launch ----------------

extern "C" void kernel_launch(void* const* d_in, const int* in_sizes, int n_in,
                              void* d_out, int out_size, void* d_ws, size_t ws_size,
                              hipStream_t stream) {
    const float* x  = (const float*)d_in[0];
    const int*   ei = (const int*)d_in[1];
    const float* W1 = (const float*)d_in[2];
    const float* b1 = (const float*)d_in[3];
    const float* W2 = (const float*)d_in[4];
    const float* b2 = (const float*)d_in[5];
    float* out = (float*)d_out;

    const int* src = ei;
    const int* dst = ei + N_EDGES;

    char* ws = (char*)d_ws;
    size_t o = 0;
    auto take = [&](size_t bytes) { char* p = ws + o; o += (bytes + 255) & ~(size_t)255; return p; };
    int*   cnt   = (int*)take(sizeof(int) * N_NODES);
    int*   rp    = (int*)take(sizeof(int) * N_NODES);
    int*   gcur  = (int*)take(sizeof(int) * (NBUCK + 1));
    float* dinv  = (float*)take(sizeof(float) * N_NODES);
    float* z     = (float*)take(sizeof(float) * N_NODES);
    int*   csrs  = (int*)take(sizeof(int) * (size_t)NBUCK * BCAP);
    unsigned short* h1 = (unsigned short*)take(sizeof(unsigned short) * (size_t)N_NODES * DIM);
    int2* ebuf_sep = (int2*)take(sizeof(int2) * (size_t)NBUCK * BCAP);
    bool fused = (o <= ws_size);
    int2* ebuf = fused ? ebuf_sep : (int2*)h1;  // fallback: alias h1 (lifetimes disjoint)

    const int NB_N = (N_NODES + 255) / 256;

    k_zero<<<2, 256, 0, stream>>>(gcur);
    if (fused) {
        k_pg<<<NB_PART + GGRID, 256, 0, stream>>>(src, dst, gcur, ebuf, x, W1, h1);
        k_csr<<<NBUCK, 256, 0, stream>>>(ebuf, gcur, rp, cnt, dinv, csrs);
    } else {
        k_part<<<NB_PART, 256, 0, stream>>>(src, dst, gcur, ebuf);
        k_csr<<<NBUCK, 256, 0, stream>>>(ebuf, gcur, rp, cnt, dinv, csrs);
        k_gemm<<<GGRID, 256, 0, stream>>>(x, W1, h1);  // after last ebuf read
    }
    k_agg1<<<N_NODES / 16, 256, 0, stream>>>(h1, dinv, rp, cnt, csrs, b1, W2, z);
    k_agg2<<<NB_N, 256, 0, stream>>>(z, dinv, rp, cnt, csrs, b2, out);
}

// Round 13
// 141.782 us; speedup vs baseline: 1.6637x; 1.0019x over previous
//
#include <hip/hip_runtime.h>

#define N_NODES 100000
#define N_EDGES 1600000
#define DIM 128

#define BSHIFT 8
#define BNODES 256
#define NBUCK 391     // ceil(100000/256)
#define BCAP  4608    // padded bucket capacity
#define PCHUNK 4096
#define NB_PART ((N_EDGES + PCHUNK - 1) / PCHUNK)  // 391

#define GTILES 1563   // ceil(100000/64)
#define GHALF  625    // gemm tiles co-dispatched with part (rest go with csr)

#define HALF_ELEMS ((size_t)N_NODES * 64)   // one 64-col half-plane of h1

typedef short s16x8 __attribute__((ext_vector_type(8)));
typedef float f32x4 __attribute__((ext_vector_type(4)));

__device__ __forceinline__ unsigned short f2bf(float f) {
    unsigned u = __float_as_uint(f);
    u += 0x7fffu + ((u >> 16) & 1u);   // RNE
    return (unsigned short)(u >> 16);
}
__device__ __forceinline__ float bflo(unsigned u) { return __uint_as_float(u << 16); }
__device__ __forceinline__ float bfhi(unsigned u) { return __uint_as_float(u & 0xffff0000u); }

__device__ __forceinline__ void acc8(float (&a)[8], uint4 v, float w) {
    a[0] = fmaf(bflo(v.x), w, a[0]); a[1] = fmaf(bfhi(v.x), w, a[1]);
    a[2] = fmaf(bflo(v.y), w, a[2]); a[3] = fmaf(bfhi(v.y), w, a[3]);
    a[4] = fmaf(bflo(v.z), w, a[4]); a[5] = fmaf(bfhi(v.z), w, a[5]);
    a[6] = fmaf(bflo(v.w), w, a[6]); a[7] = fmaf(bfhi(v.w), w, a[7]);
}

// ---------------- CSR build (padded buckets) ----------------

__global__ void k_zero(int* __restrict__ gcur) {
    int t = blockIdx.x * blockDim.x + threadIdx.x;
    if (t < NBUCK) gcur[t] = t * BCAP;
}

__device__ __forceinline__ void part_body(char* smem, int bid,
                                          const int* __restrict__ src,
                                          const int* __restrict__ dst,
                                          int* __restrict__ gcur,
                                          int2* __restrict__ ebuf) {
    int* hist = (int*)smem;
    int* gbase = hist + NBUCK;
    int tid = threadIdx.x;
    long e0 = (long)bid * PCHUNK;
    int n = min(PCHUNK, (int)(N_EDGES - e0));
    for (int b = tid; b < NBUCK; b += 256) hist[b] = 0;
    __syncthreads();

    int mys[16], myd[16];
#pragma unroll
    for (int k = 0; k < 16; ++k) {
        int idx = k * 256 + tid;
        if (idx < n) {
            mys[k] = src[e0 + idx];
            myd[k] = dst[e0 + idx];
            atomicAdd(&hist[myd[k] >> BSHIFT], 1);
        } else {
            myd[k] = -1;
        }
    }
    __syncthreads();
    for (int b = tid; b < NBUCK; b += 256) {
        gbase[b] = hist[b] ? atomicAdd(&gcur[b], hist[b]) : 0;
        hist[b] = 0;
    }
    __syncthreads();
#pragma unroll
    for (int k = 0; k < 16; ++k) {
        if (myd[k] >= 0) {
            int b = myd[k] >> BSHIFT;
            int slot = gbase[b] + atomicAdd(&hist[b], 1);
            ebuf[slot] = make_int2(mys[k], myd[k]);
        }
    }
}

// merged CSR body: count, scan, emit src-only lists (one bucket per block)
__device__ __forceinline__ void csr_body(char* smem, int b,
                                         const int2* __restrict__ ebuf,
                                         const int* __restrict__ gcur,
                                         int* __restrict__ rp,
                                         int* __restrict__ cnt,
                                         float* __restrict__ dinv,
                                         int* __restrict__ csrs) {
    int* lcnt = (int*)smem;
    int* lcur = lcnt + BNODES;
    int t = threadIdx.x;
    int node0 = b << BSHIFT;
    lcnt[t] = 0;
    __syncthreads();
    int base = b * BCAP, end = gcur[b];
    for (int e = base + t; e < end; e += 256)
        atomicAdd(&lcnt[ebuf[e].y - node0], 1);
    __syncthreads();
    int c = lcnt[t];
    lcur[t] = c;
    __syncthreads();
    for (int s = 1; s < 256; s <<= 1) {
        int u = (t >= s) ? lcur[t - s] : 0;
        __syncthreads();
        lcur[t] += u;
        __syncthreads();
    }
    int excl = lcur[t] - c;
    lcur[t] = excl;           // becomes emit cursor
    int node = node0 + t;
    if (node < N_NODES) {
        rp[node] = base + excl;
        cnt[node] = c;
        dinv[node] = rsqrtf((float)(c + 1));
    }
    __syncthreads();
    for (int e = base + t; e < end; e += 256) {
        int2 d = ebuf[e];
        int p = atomicAdd(&lcur[d.y - node0], 1);
        csrs[base + p] = d.x;
    }
}

// ---- GEMM body: h1h(bf16, [2][N][64] half-planes) = x @ W1, one 64-row tile ----
__device__ __forceinline__ void gemm_body(char* smem, int tile,
                                          const float* __restrict__ x,
                                          const float* __restrict__ W1,
                                          unsigned short* __restrict__ h1h) {
    if (tile >= GTILES) return;
    unsigned short* Wt = (unsigned short*)smem;           // 32 KB
    int tid = threadIdx.x;
    for (int idx = tid; idx < DIM * DIM; idx += 256) {
        int k = idx >> 7, c = idx & 127;
        Wt[c * 128 + (k ^ ((c & 7) << 3))] = f2bf(W1[idx]);
    }
    __syncthreads();

    int wv = tid >> 6, lane = tid & 63;
    int g = lane >> 4, tl = lane & 15;
    unsigned short* cst = (unsigned short*)(smem + 32768 + wv * 4096);

    int rb = tile * 64 + wv * 16;
    if (rb >= N_NODES) return;

    s16x8 afrag[4];
    const float* xrow = x + (size_t)(rb + tl) * DIM + g * 8;
#pragma unroll
    for (int kc = 0; kc < 4; ++kc) {
        float4 p0 = *(const float4*)(xrow + kc * 32);
        float4 p1 = *(const float4*)(xrow + kc * 32 + 4);
        s16x8 a;
        a[0] = (short)f2bf(p0.x); a[1] = (short)f2bf(p0.y);
        a[2] = (short)f2bf(p0.z); a[3] = (short)f2bf(p0.w);
        a[4] = (short)f2bf(p1.x); a[5] = (short)f2bf(p1.y);
        a[6] = (short)f2bf(p1.z); a[7] = (short)f2bf(p1.w);
        afrag[kc] = a;
    }

    f32x4 acc[8];
#pragma unroll
    for (int ct = 0; ct < 8; ++ct) acc[ct] = (f32x4)0.0f;
#pragma unroll
    for (int kc = 0; kc < 4; ++kc) {
#pragma unroll
        for (int ct = 0; ct < 8; ++ct) {
            int crow = ct * 16 + tl;
            int boff = crow * 256 + ((kc * 64 + g * 16) ^ ((crow & 7) << 4));
            s16x8 b = *(const s16x8*)((const char*)Wt + boff);
            acc[ct] = __builtin_amdgcn_mfma_f32_16x16x32_bf16(afrag[kc], b, acc[ct], 0, 0, 0);
        }
    }

#pragma unroll
    for (int ct = 0; ct < 8; ++ct) {
#pragma unroll
        for (int r = 0; r < 4; ++r) {
            float own = acc[ct][r];
            float oth = __shfl_xor(own, 1, 64);
            if ((lane & 1) == 0) {
                unsigned pk = (unsigned)f2bf(own) | ((unsigned)f2bf(oth) << 16);
                int row = g * 4 + r;
                int col = ct * 16 + tl;
                *(unsigned*)&cst[row * 128 + (col ^ (row << 3))] = pk;
            }
        }
    }
    asm volatile("s_waitcnt lgkmcnt(0)" ::: "memory");

    int hf = tl >> 3, ch = (tl & 7) * 8;   // half-plane / col-within-half
#pragma unroll
    for (int c = 0; c < 4; ++c) {
        int row = c * 4 + g;
        uint4 v = *(const uint4*)&cst[row * 128 + ((tl ^ row) * 8)];
        *(uint4*)(h1h + (size_t)hf * HALF_ELEMS + (size_t)(rb + row) * 64 + ch) = v;
    }
}

// standalone kernels (fallback path when ws is tight)
__global__ __launch_bounds__(256) void k_part(const int* __restrict__ src,
                                              const int* __restrict__ dst,
                                              int* __restrict__ gcur,
                                              int2* __restrict__ ebuf) {
    __shared__ __align__(16) char smem[2 * NBUCK * 4 + 16];
    part_body(smem, blockIdx.x, src, dst, gcur, ebuf);
}

__global__ __launch_bounds__(256) void k_gemm(const float* __restrict__ x,
                                              const float* __restrict__ W1,
                                              unsigned short* __restrict__ h1h) {
    __shared__ __align__(16) char smem[49152];
    gemm_body(smem, blockIdx.x, x, W1, h1h);
}

__global__ __launch_bounds__(256) void k_csrk(const int2* __restrict__ ebuf,
                                              const int* __restrict__ gcur,
                                              int* __restrict__ rp,
                                              int* __restrict__ cnt,
                                              float* __restrict__ dinv,
                                              int* __restrict__ csrs) {
    __shared__ __align__(16) char smem[2 * BNODES * 4];
    csr_body(smem, blockIdx.x, ebuf, gcur, rp, cnt, dinv, csrs);
}

// fused D1: part || gemm tiles [0, GHALF)
__global__ __launch_bounds__(256) void k_pg1(const int* __restrict__ src,
                                             const int* __restrict__ dst,
                                             int* __restrict__ gcur,
                                             int2* __restrict__ ebuf,
                                             const float* __restrict__ x,
                                             const float* __restrict__ W1,
                                             unsigned short* __restrict__ h1h) {
    __shared__ __align__(16) char smem[49152];
    if (blockIdx.x < NB_PART) part_body(smem, blockIdx.x, src, dst, gcur, ebuf);
    else                      gemm_body(smem, blockIdx.x - NB_PART, x, W1, h1h);
}

// fused D2: csr || gemm tiles [GHALF, GTILES)
__global__ __launch_bounds__(256) void k_pg2(const int2* __restrict__ ebuf,
                                             const int* __restrict__ gcur,
                                             int* __restrict__ rp,
                                             int* __restrict__ cnt,
                                             float* __restrict__ dinv,
                                             int* __restrict__ csrs,
                                             const float* __restrict__ x,
                                             const float* __restrict__ W1,
                                             unsigned short* __restrict__ h1h) {
    __shared__ __align__(16) char smem[49152];
    if (blockIdx.x < NBUCK) csr_body(smem, blockIdx.x, ebuf, gcur, rp, cnt, dinv, csrs);
    else                    gemm_body(smem, GHALF + (blockIdx.x - NBUCK), x, W1, h1h);
}

// ---------------- agg1 halved: zpart[half][i], half = blockIdx&1 -> XCD parity ----------------
// R7 structure at half width: 8-lane group per node (8 nodes/wave), lane owns 8 cols,
// 128B coalesced row gathers from the 12.8MB half-plane, serial unroll x4.

__global__ __launch_bounds__(256) void k_agg1h(const unsigned short* __restrict__ h1h,
                                               const float* __restrict__ dinv,
                                               const int* __restrict__ rp,
                                               const int* __restrict__ cnt,
                                               const int* __restrict__ csrs,
                                               const float* __restrict__ b1,
                                               const float* __restrict__ W2,
                                               float* __restrict__ zpart) {
    int half = blockIdx.x & 1;
    int nb = blockIdx.x >> 1;            // 0..3124
    int lane = threadIdx.x & 63;
    int wv = threadIdx.x >> 6;
    int g = lane >> 3, tl = lane & 7;
    int i = nb * 32 + wv * 8 + g;
    int c0 = tl * 8;                     // col within half
    const unsigned short* hbase = h1h + (size_t)half * HALF_ELEMS + c0;
    float di = dinv[i];
    int beg = rp[i], end = beg + cnt[i];
    float a[8];
#pragma unroll
    for (int q = 0; q < 8; ++q) a[q] = 0.f;

    int j = beg;
    for (; j + 4 <= end; j += 4) {
        int s0 = csrs[j], s1 = csrs[j + 1], s2 = csrs[j + 2], s3 = csrs[j + 3];
        uint4 v0 = *(const uint4*)(hbase + (size_t)s0 * 64);
        uint4 v1 = *(const uint4*)(hbase + (size_t)s1 * 64);
        uint4 v2 = *(const uint4*)(hbase + (size_t)s2 * 64);
        uint4 v3 = *(const uint4*)(hbase + (size_t)s3 * 64);
        float w0 = dinv[s0] * di, w1 = dinv[s1] * di;
        float w2 = dinv[s2] * di, w3 = dinv[s3] * di;
        acc8(a, v0, w0);
        acc8(a, v1, w1);
        acc8(a, v2, w2);
        acc8(a, v3, w3);
    }
    for (; j < end; ++j) {
        int s0 = csrs[j];
        uint4 v0 = *(const uint4*)(hbase + (size_t)s0 * 64);
        acc8(a, v0, dinv[s0] * di);
    }

    uint4 vs = *(const uint4*)(hbase + (size_t)i * 64);
    float sii = di * di;
    int cb = half * 64 + c0;
    float4 bA = *(const float4*)(b1 + cb);
    float4 bB = *(const float4*)(b1 + cb + 4);
    float4 wA = *(const float4*)(W2 + cb);
    float4 wB = *(const float4*)(W2 + cb + 4);
    float p = 0.f;
    p += fmaxf(fmaf(bflo(vs.x), sii, a[0]) + bA.x, 0.f) * wA.x;
    p += fmaxf(fmaf(bfhi(vs.x), sii, a[1]) + bA.y, 0.f) * wA.y;
    p += fmaxf(fmaf(bflo(vs.y), sii, a[2]) + bA.z, 0.f) * wA.z;
    p += fmaxf(fmaf(bfhi(vs.y), sii, a[3]) + bA.w, 0.f) * wA.w;
    p += fmaxf(fmaf(bflo(vs.z), sii, a[4]) + bB.x, 0.f) * wB.x;
    p += fmaxf(fmaf(bfhi(vs.z), sii, a[5]) + bB.y, 0.f) * wB.y;
    p += fmaxf(fmaf(bflo(vs.w), sii, a[6]) + bB.z, 0.f) * wB.z;
    p += fmaxf(fmaf(bfhi(vs.w), sii, a[7]) + bB.w, 0.f) * wB.w;
#pragma unroll
    for (int off = 4; off >= 1; off >>= 1) p += __shfl_xor(p, off, 64);
    if (tl == 0) zpart[(size_t)half * N_NODES + i] = p;
}

// z[i] = zpart[0][i] + zpart[1][i]
__global__ void k_zred(const float* __restrict__ zpart, float* __restrict__ z) {
    int i = blockIdx.x * blockDim.x + threadIdx.x;
    if (i < N_NODES) z[i] = zpart[i] + zpart[N_NODES + i];
}

// ---------------- agg2: src-only meta, w recomputed ----------------

__global__ __launch_bounds__(256) void k_agg2(const float* __restrict__ zin,
                                              const float* __restrict__ dinv,
                                              const int* __restrict__ rp,
                                              const int* __restrict__ cnt,
                                              const int* __restrict__ csrs,
                                              const float* __restrict__ b2,
                                              float* __restrict__ out) {
    int i = blockIdx.x * blockDim.x + threadIdx.x;
    if (i >= N_NODES) return;
    float di = dinv[i];
    int beg = rp[i], end = beg + cnt[i];
    float acc = 0.f;
    int j = beg;
    for (; j + 4 <= end; j += 4) {
        int s0 = csrs[j], s1 = csrs[j + 1], s2 = csrs[j + 2], s3 = csrs[j + 3];
        float z0 = zin[s0], z1 = zin[s1], z2 = zin[s2], z3 = zin[s3];
        acc = fmaf(z0, dinv[s0] * di, acc);
        acc = fmaf(z1, dinv[s1] * di, acc);
        acc = fmaf(z2, dinv[s2] * di, acc);
        acc = fmaf(z3, dinv[s3] * di, acc);
    }
    for (; j < end; ++j) {
        int s0 = csrs[j];
        acc = fmaf(zin[s0], dinv[s0] * di, acc);
    }
    out[i] = acc + zin[i] * di * di + b2[0];
}

// ---------------- launch ----------------

extern "C" void kernel_launch(void* const* d_in, const int* in_sizes, int n_in,
                              void* d_out, int out_size, void* d_ws, size_t ws_size,
                              hipStream_t stream) {
    const float* x  = (const float*)d_in[0];
    const int*   ei = (const int*)d_in[1];
    const float* W1 = (const float*)d_in[2];
    const float* b1 = (const float*)d_in[3];
    const float* W2 = (const float*)d_in[4];
    const float* b2 = (const float*)d_in[5];
    float* out = (float*)d_out;

    const int* src = ei;
    const int* dst = ei + N_EDGES;

    char* ws = (char*)d_ws;
    size_t o = 0;
    auto take = [&](size_t bytes) { char* p = ws + o; o += (bytes + 255) & ~(size_t)255; return p; };
    int*   cnt   = (int*)take(sizeof(int) * N_NODES);
    int*   rp    = (int*)take(sizeof(int) * N_NODES);
    int*   gcur  = (int*)take(sizeof(int) * (NBUCK + 1));
    float* dinv  = (float*)take(sizeof(float) * N_NODES);
    float* z     = (float*)take(sizeof(float) * N_NODES);
    float* zpart = (float*)take(sizeof(float) * 2 * N_NODES);
    int*   csrs  = (int*)take(sizeof(int) * (size_t)NBUCK * BCAP);
    unsigned short* h1h = (unsigned short*)take(sizeof(unsigned short) * 2 * HALF_ELEMS);
    int2* ebuf_sep = (int2*)take(sizeof(int2) * (size_t)NBUCK * BCAP);
    bool fused = (o <= ws_size);
    int2* ebuf = fused ? ebuf_sep : (int2*)h1h;  // fallback: alias h1h (lifetimes disjoint)

    const int NB_N = (N_NODES + 255) / 256;

    k_zero<<<2, 256, 0, stream>>>(gcur);
    if (fused) {
        k_pg1<<<NB_PART + GHALF, 256, 0, stream>>>(src, dst, gcur, ebuf, x, W1, h1h);
        k_pg2<<<NBUCK + (GTILES - GHALF), 256, 0, stream>>>(ebuf, gcur, rp, cnt, dinv, csrs, x, W1, h1h);
    } else {
        k_part<<<NB_PART, 256, 0, stream>>>(src, dst, gcur, ebuf);
        k_csrk<<<NBUCK, 256, 0, stream>>>(ebuf, gcur, rp, cnt, dinv, csrs);
        k_gemm<<<GTILES, 256, 0, stream>>>(x, W1, h1h);  // after last ebuf read
    }
    k_agg1h<<<2 * (N_NODES / 32), 256, 0, stream>>>(h1h, dinv, rp, cnt, csrs, b1, W2, zpart);
    k_zred<<<NB_N, 256, 0, stream>>>(zpart, z);
    k_agg2<<<NB_N, 256, 0, stream>>>(z, dinv, rp, cnt, csrs, b2, out);
}